// Round 1
// baseline (250.030 us; speedup 1.0000x reference)
//
#include <hip/hip_runtime.h>
#include <hip/hip_fp16.h>
#include <cmath>

#define B_SZ 2048
#define D_IN 512
#define U_N  512
#define M_B  8
#define FD   1024   // D_IN + U_N
#define NRU  4096   // U_N * M_B

typedef _Float16 f16x8 __attribute__((ext_vector_type(8)));
typedef float    f32x4 __attribute__((ext_vector_type(4)));

// ---------------------------------------------------------------------------
// P1: h = sum_m state[b,u,m]; fused = [f16(inputs), f16(h)]; reset[:,0:512]=f16(inputs)
// grid: 2048 blocks x 256 threads
// ---------------------------------------------------------------------------
__global__ __launch_bounds__(256) void prep_kernel(
    const float* __restrict__ inputs, const float* __restrict__ state,
    __half* __restrict__ fused, __half* __restrict__ reset)
{
    const int b = blockIdx.x;
    const int t = threadIdx.x;

    // inputs part: 2 cols per thread
    const float2 iv = *(const float2*)(inputs + (size_t)b * D_IN + t * 2);
    __half2 hv;
    hv.x = __float2half(iv.x);
    hv.y = __float2half(iv.y);
    *(__half2*)(fused + (size_t)b * FD + t * 2) = hv;
    *(__half2*)(reset + (size_t)b * FD + t * 2) = hv;

    // h part: units 2t, 2t+1  -> state[b, u*8 .. u*8+7]
    const float4* sp = (const float4*)(state + (size_t)b * NRU + t * 16);
    float4 x0 = sp[0], x1 = sp[1], x2 = sp[2], x3 = sp[3];
    float s0 = (x0.x + x0.y) + (x0.z + x0.w) + (x1.x + x1.y) + (x1.z + x1.w);
    float s1 = (x2.x + x2.y) + (x2.z + x2.w) + (x3.x + x3.y) + (x3.z + x3.w);
    __half2 h2;
    h2.x = __float2half(s0);
    h2.y = __float2half(s1);
    *(__half2*)(fused + (size_t)b * FD + D_IN + t * 2) = h2;
}

// ---------------------------------------------------------------------------
// P2: Wt[n][k] = f16(W[k][n]);  W is [K,N] fp32, Wt is [N,K] f16
// grid: dim3(N/32, K/32) x 256 threads
// ---------------------------------------------------------------------------
__global__ __launch_bounds__(256) void convT_kernel(
    const float* __restrict__ W, __half* __restrict__ Wt, int K, int N)
{
    __shared__ float tile[32][33];
    const int kt = blockIdx.y * 32;
    const int nt = blockIdx.x * 32;
    const int t  = threadIdx.x;
    const int c  = t & 31;
    const int r4 = t >> 5;   // 0..7

#pragma unroll
    for (int i = 0; i < 4; i++) {
        int r = r4 + i * 8;
        tile[r][c] = W[(size_t)(kt + r) * N + nt + c];
    }
    __syncthreads();
#pragma unroll
    for (int i = 0; i < 4; i++) {
        int rr = r4 + i * 8;               // local n
        Wt[(size_t)(nt + rr) * K + kt + c] = __float2half(tile[c][rr]);
    }
}

// ---------------------------------------------------------------------------
// GEMM: C[M,N] = A[M,K](f16) @ Bt[N,K](f16)^T + bias, optional tanh.
// 128x128 tile, BK=32, 256 threads (4 waves, each 64x64 via 4x4 mfma 16x16x32)
// ---------------------------------------------------------------------------
template <int ACT>
__global__ __launch_bounds__(256) void gemm_f16_nt(
    const __half* __restrict__ A, const __half* __restrict__ Bt,
    const float* __restrict__ bias, float* __restrict__ C,
    int Ncols, int K)
{
    __shared__ __align__(16) __half sA[128][40];
    __shared__ __align__(16) __half sB[128][40];

    const int t    = threadIdx.x;
    const int m0   = blockIdx.y << 7;
    const int n0   = blockIdx.x << 7;
    const int lane = t & 63;
    const int w    = t >> 6;
    const int m16  = lane & 15;
    const int quad = lane >> 4;
    const int wm   = (w & 1) << 6;
    const int wn   = (w >> 1) << 6;

    f32x4 acc[4][4];
#pragma unroll
    for (int i = 0; i < 4; i++)
#pragma unroll
        for (int j = 0; j < 4; j++)
#pragma unroll
            for (int r = 0; r < 4; r++) acc[i][j][r] = 0.f;

    const int r0 = t >> 2;          // 0..63
    const int s0 = (t & 3) * 8;     // half-offset in row: 0,8,16,24

    const __half* Arow0 = A  + (size_t)(m0 + r0) * K + s0;
    const __half* Arow1 = Arow0 + (size_t)64 * K;
    const __half* Brow0 = Bt + (size_t)(n0 + r0) * K + s0;
    const __half* Brow1 = Brow0 + (size_t)64 * K;

    for (int kt = 0; kt < K; kt += 32) {
        uint4 a0 = *(const uint4*)(Arow0 + kt);
        uint4 a1 = *(const uint4*)(Arow1 + kt);
        uint4 b0 = *(const uint4*)(Brow0 + kt);
        uint4 b1 = *(const uint4*)(Brow1 + kt);
        __syncthreads();
        *(uint4*)&sA[r0][s0]      = a0;
        *(uint4*)&sA[r0 + 64][s0] = a1;
        *(uint4*)&sB[r0][s0]      = b0;
        *(uint4*)&sB[r0 + 64][s0] = b1;
        __syncthreads();

        f16x8 af[4], bf[4];
#pragma unroll
        for (int mi = 0; mi < 4; mi++)
            af[mi] = *(const f16x8*)&sA[wm + mi * 16 + m16][quad * 8];
#pragma unroll
        for (int ni = 0; ni < 4; ni++)
            bf[ni] = *(const f16x8*)&sB[wn + ni * 16 + m16][quad * 8];
#pragma unroll
        for (int mi = 0; mi < 4; mi++)
#pragma unroll
            for (int ni = 0; ni < 4; ni++)
                acc[mi][ni] = __builtin_amdgcn_mfma_f32_16x16x32_f16(
                    af[mi], bf[ni], acc[mi][ni], 0, 0, 0);
    }

#pragma unroll
    for (int mi = 0; mi < 4; mi++) {
#pragma unroll
        for (int ni = 0; ni < 4; ni++) {
            const int col = n0 + wn + ni * 16 + m16;
            const float bv = bias[col];
#pragma unroll
            for (int r = 0; r < 4; r++) {
                const int row = m0 + wm + mi * 16 + quad * 4 + r;
                float v = acc[mi][ni][r] + bv;
                if (ACT == 1) v = tanhf(v);
                C[(size_t)row * Ncols + col] = v;
            }
        }
    }
}

// ---------------------------------------------------------------------------
// E1: rki = softmax_M(-(ln_r - tab)^2); q = sum rki*h_hat; reset[:,512+u] = f16(q)
// ---------------------------------------------------------------------------
__global__ __launch_bounds__(256) void gate_r_kernel(
    const float* __restrict__ ln_r, const float* __restrict__ state,
    __half* __restrict__ reset)
{
    const int idx = blockIdx.x * 256 + threadIdx.x;
    const int b = idx >> 9;
    const int u = idx & 511;

    const float TAB[8] = {0.0f, 1.15129254649702f, 2.30258509299405f,
                          3.45387763949107f, 4.60517018598809f, 5.75646273248511f,
                          6.90775527898214f, 8.05904782547916f};

    const float4* xr = (const float4*)(ln_r + ((size_t)b * NRU + u * 8));
    const float4* hh = (const float4*)(state + ((size_t)b * NRU + u * 8));
    float4 x0 = xr[0], x1 = xr[1];
    float4 h0 = hh[0], h1 = hh[1];
    float x[8] = {x0.x, x0.y, x0.z, x0.w, x1.x, x1.y, x1.z, x1.w};
    float h[8] = {h0.x, h0.y, h0.z, h0.w, h1.x, h1.y, h1.z, h1.w};

    float s[8];
    float mx = -1e30f;
#pragma unroll
    for (int i = 0; i < 8; i++) {
        float d = x[i] - TAB[i];
        s[i] = -d * d;
        mx = fmaxf(mx, s[i]);
    }
    float sum = 0.f, qn = 0.f;
#pragma unroll
    for (int i = 0; i < 8; i++) {
        float e = expf(s[i] - mx);
        sum += e;
        qn += e * h[i];
    }
    float q = qn / sum;
    reset[(size_t)b * FD + D_IN + u] = __float2half(q);
}

// ---------------------------------------------------------------------------
// E2: ski softmax; exp decay; h_hat_next; h_next
// ---------------------------------------------------------------------------
__global__ __launch_bounds__(256) void final_kernel(
    const float* __restrict__ ln_u, const float* __restrict__ state,
    const float* __restrict__ qk, const float* __restrict__ elapsed,
    float* __restrict__ out0, float* __restrict__ out1)
{
    const int idx = blockIdx.x * 256 + threadIdx.x;
    const int b = idx >> 9;
    const int u = idx & 511;

    const float TAB[8] = {0.0f, 1.15129254649702f, 2.30258509299405f,
                          3.45387763949107f, 4.60517018598809f, 5.75646273248511f,
                          6.90775527898214f, 8.05904782547916f};
    const float INV_TAU[8] = {1.0f, 0.316227766016838f, 0.1f, 0.0316227766016838f,
                              0.01f, 0.00316227766016838f, 0.001f, 0.000316227766016838f};

    const float4* xr = (const float4*)(ln_u + ((size_t)b * NRU + u * 8));
    const float4* hh = (const float4*)(state + ((size_t)b * NRU + u * 8));
    float4 x0 = xr[0], x1 = xr[1];
    float4 h0 = hh[0], h1 = hh[1];
    float x[8] = {x0.x, x0.y, x0.z, x0.w, x1.x, x1.y, x1.z, x1.w};
    float h[8] = {h0.x, h0.y, h0.z, h0.w, h1.x, h1.y, h1.z, h1.w};

    const float q  = qk[(size_t)b * U_N + u];
    const float el = elapsed[b];

    float s[8];
    float mx = -1e30f;
#pragma unroll
    for (int i = 0; i < 8; i++) {
        float d = x[i] - TAB[i];
        s[i] = -d * d;
        mx = fmaxf(mx, s[i]);
    }
    float e[8];
    float sum = 0.f;
#pragma unroll
    for (int i = 0; i < 8; i++) {
        e[i] = expf(s[i] - mx);
        sum += e[i];
    }
    const float inv_sum = 1.0f / sum;

    float hn[8];
    float acc = 0.f;
#pragma unroll
    for (int i = 0; i < 8; i++) {
        float sk = e[i] * inv_sum;
        float et = expf(-el * INV_TAU[i]);
        hn[i] = ((1.0f - sk) * h[i] + sk * q) * et;
        acc += hn[i];
    }

    float4* o = (float4*)(out1 + ((size_t)b * NRU + u * 8));
    o[0] = make_float4(hn[0], hn[1], hn[2], hn[3]);
    o[1] = make_float4(hn[4], hn[5], hn[6], hn[7]);
    out0[(size_t)b * U_N + u] = acc;
}

// ---------------------------------------------------------------------------
extern "C" void kernel_launch(void* const* d_in, const int* in_sizes, int n_in,
                              void* d_out, int out_size, void* d_ws, size_t ws_size,
                              hipStream_t stream)
{
    (void)in_sizes; (void)n_in; (void)out_size; (void)ws_size;

    const float* inputs  = (const float*)d_in[0];
    const float* elapsed = (const float*)d_in[1];
    const float* state   = (const float*)d_in[2];
    const float* W_r     = (const float*)d_in[3];
    const float* b_r     = (const float*)d_in[4];
    const float* W_d     = (const float*)d_in[5];
    const float* b_d     = (const float*)d_in[6];
    const float* W_u     = (const float*)d_in[7];
    const float* b_u     = (const float*)d_in[8];
    float* out = (float*)d_out;

    char* ws = (char*)d_ws;
    __half* fused = (__half*)(ws);                         //  4 MB  [2048,1024]
    __half* reset = (__half*)(ws + ((size_t)4  << 20));    //  4 MB  [2048,1024]
    __half* WrT   = (__half*)(ws + ((size_t)8  << 20));    //  8 MB  [4096,1024]
    __half* WuT   = (__half*)(ws + ((size_t)16 << 20));    //  8 MB  [4096,1024]
    __half* WdT   = (__half*)(ws + ((size_t)24 << 20));    //  1 MB  [512,1024]
    float*  ln_r  = (float*) (ws + ((size_t)25 << 20));    // 32 MB  [2048,4096]
    float*  ln_u  = (float*) (ws + ((size_t)57 << 20));    // 32 MB  [2048,4096]
    float*  qk    = (float*) (ws + ((size_t)89 << 20));    //  4 MB  [2048,512]

    prep_kernel<<<B_SZ, 256, 0, stream>>>(inputs, state, fused, reset);
    convT_kernel<<<dim3(NRU / 32, FD / 32), 256, 0, stream>>>(W_r, WrT, FD, NRU);
    convT_kernel<<<dim3(NRU / 32, FD / 32), 256, 0, stream>>>(W_u, WuT, FD, NRU);
    convT_kernel<<<dim3(U_N / 32, FD / 32), 256, 0, stream>>>(W_d, WdT, FD, U_N);

    gemm_f16_nt<0><<<dim3(NRU / 128, B_SZ / 128), 256, 0, stream>>>(fused, WrT, b_r, ln_r, NRU, FD);
    gemm_f16_nt<0><<<dim3(NRU / 128, B_SZ / 128), 256, 0, stream>>>(fused, WuT, b_u, ln_u, NRU, FD);

    gate_r_kernel<<<(B_SZ * U_N) / 256, 256, 0, stream>>>(ln_r, state, reset);

    gemm_f16_nt<1><<<dim3(U_N / 128, B_SZ / 128), 256, 0, stream>>>(reset, WdT, b_d, qk, U_N, FD);

    final_kernel<<<(B_SZ * U_N) / 256, 256, 0, stream>>>(ln_u, state, qk, elapsed, out,
                                                         out + (size_t)B_SZ * U_N);
}

// Round 2
// 232.927 us; speedup vs baseline: 1.0734x; 1.0734x over previous
//
#include <hip/hip_runtime.h>
#include <hip/hip_fp16.h>
#include <cmath>

#define B_SZ 2048
#define D_IN 512
#define U_N  512
#define M_B  8
#define FD   1024   // D_IN + U_N
#define NRU  4096   // U_N * M_B
#define NRU2 8192   // combined r+u output cols

typedef _Float16 f16x8 __attribute__((ext_vector_type(8)));
typedef float    f32x4 __attribute__((ext_vector_type(4)));

typedef const __attribute__((address_space(1))) void glb_cv;
typedef __attribute__((address_space(3))) void lds_v;

// ---------------------------------------------------------------------------
// P1: h = sum_m state[b,u,m]; fused = [f16(inputs), f16(h)]; reset[:,0:512]=f16(inputs)
// ---------------------------------------------------------------------------
__global__ __launch_bounds__(256) void prep_kernel(
    const float* __restrict__ inputs, const float* __restrict__ state,
    __half* __restrict__ fused, __half* __restrict__ reset)
{
    const int b = blockIdx.x;
    const int t = threadIdx.x;

    const float2 iv = *(const float2*)(inputs + (size_t)b * D_IN + t * 2);
    __half2 hv;
    hv.x = __float2half(iv.x);
    hv.y = __float2half(iv.y);
    *(__half2*)(fused + (size_t)b * FD + t * 2) = hv;
    *(__half2*)(reset + (size_t)b * FD + t * 2) = hv;

    const float4* sp = (const float4*)(state + (size_t)b * NRU + t * 16);
    float4 x0 = sp[0], x1 = sp[1], x2 = sp[2], x3 = sp[3];
    float s0 = (x0.x + x0.y) + (x0.z + x0.w) + (x1.x + x1.y) + (x1.z + x1.w);
    float s1 = (x2.x + x2.y) + (x2.z + x2.w) + (x3.x + x3.y) + (x3.z + x3.w);
    __half2 h2;
    h2.x = __float2half(s0);
    h2.y = __float2half(s1);
    *(__half2*)(fused + (size_t)b * FD + D_IN + t * 2) = h2;
}

// ---------------------------------------------------------------------------
// P2: Wt[n][k] = f16(W[k][n]);  W is [K,N] fp32, Wt is [N,K] f16
// ---------------------------------------------------------------------------
__global__ __launch_bounds__(256) void convT_kernel(
    const float* __restrict__ W, __half* __restrict__ Wt, int K, int N)
{
    __shared__ float tile[32][33];
    const int kt = blockIdx.y * 32;
    const int nt = blockIdx.x * 32;
    const int t  = threadIdx.x;
    const int c  = t & 31;
    const int r4 = t >> 5;

#pragma unroll
    for (int i = 0; i < 4; i++) {
        int r = r4 + i * 8;
        tile[r][c] = W[(size_t)(kt + r) * N + nt + c];
    }
    __syncthreads();
#pragma unroll
    for (int i = 0; i < 4; i++) {
        int rr = r4 + i * 8;
        Wt[(size_t)(nt + rr) * K + kt + c] = __float2half(tile[c][rr]);
    }
}

// ---------------------------------------------------------------------------
// GEMM: C[M,N] = A[M,K](f16) @ Bt[N,K](f16)^T + bias, optional tanh.
// BM x 128 tile, BK=32, 256 threads (4 waves). global_load_lds width-16
// staging into unpadded [rows][32] LDS (m97 structure, 2-barrier K-loop).
// BM=128: wave = 64x64 (4x4 frags).  BM=64: wave = 32x64 (2x4 frags).
// ---------------------------------------------------------------------------
template <int BM, int ACT>
__global__ __launch_bounds__(256) void gemm_lds(
    const __half* __restrict__ A, const __half* __restrict__ Bt,
    const float* __restrict__ biasA, const float* __restrict__ biasB, int nsplit,
    float* __restrict__ C, int Ncols, int K)
{
    __shared__ __align__(16) __half sA[BM][32];
    __shared__ __align__(16) __half sB[128][32];

    const int t    = threadIdx.x;
    const int m0   = blockIdx.y * BM;
    const int n0   = blockIdx.x << 7;
    const int lane = t & 63;
    const int w    = t >> 6;
    const int m16  = lane & 15;
    const int quad = lane >> 4;
    constexpr int MI = BM / 32;            // m-frags per wave: 4 or 2
    constexpr int IA = BM / 64;            // global_load_lds instrs per wave for A
    const int wm = (w & 1) * (BM / 2);
    const int wn = (w >> 1) << 6;

    f32x4 acc[MI][4];
#pragma unroll
    for (int i = 0; i < MI; i++)
#pragma unroll
        for (int j = 0; j < 4; j++)
#pragma unroll
            for (int r = 0; r < 4; r++) acc[i][j][r] = 0.f;

    // staging address setup: wave w owns contiguous LDS chunk, lane l -> +l*16B
    const __half* gAp[IA];
    const __half* lAp[IA];
#pragma unroll
    for (int i = 0; i < IA; i++) {
        const int off = w * (BM * 16) + i * 1024 + lane * 16;  // byte off in tile
        const int row = off >> 6;
        const int kc  = (off & 63) >> 1;
        gAp[i] = A + (size_t)(m0 + row) * K + kc;
        lAp[i] = &sA[0][0] + ((w * (BM * 16) + i * 1024) >> 1);
    }
    const __half* gBp[2];
    const __half* lBp[2];
#pragma unroll
    for (int i = 0; i < 2; i++) {
        const int off = w * 2048 + i * 1024 + lane * 16;
        const int row = off >> 6;
        const int kc  = (off & 63) >> 1;
        gBp[i] = Bt + (size_t)(n0 + row) * K + kc;
        lBp[i] = &sB[0][0] + ((w * 2048 + i * 1024) >> 1);
    }

    for (int kt = 0; kt < K; kt += 32) {
        __syncthreads();   // all waves done reading previous tile
#pragma unroll
        for (int i = 0; i < IA; i++)
            __builtin_amdgcn_global_load_lds((glb_cv*)(gAp[i] + kt), (lds_v*)lAp[i], 16, 0, 0);
#pragma unroll
        for (int i = 0; i < 2; i++)
            __builtin_amdgcn_global_load_lds((glb_cv*)(gBp[i] + kt), (lds_v*)lBp[i], 16, 0, 0);
        __syncthreads();   // loads landed (vmcnt drained by barrier)

        f16x8 af[MI], bf[4];
#pragma unroll
        for (int mi = 0; mi < MI; mi++)
            af[mi] = *(const f16x8*)&sA[wm + mi * 16 + m16][quad * 8];
#pragma unroll
        for (int ni = 0; ni < 4; ni++)
            bf[ni] = *(const f16x8*)&sB[wn + ni * 16 + m16][quad * 8];
#pragma unroll
        for (int mi = 0; mi < MI; mi++)
#pragma unroll
            for (int ni = 0; ni < 4; ni++)
                acc[mi][ni] = __builtin_amdgcn_mfma_f32_16x16x32_f16(
                    af[mi], bf[ni], acc[mi][ni], 0, 0, 0);
    }

    const float* bp  = (n0 < nsplit) ? biasA : biasB;
    const int    cb0 = (n0 < nsplit) ? n0 : n0 - nsplit;
#pragma unroll
    for (int mi = 0; mi < MI; mi++) {
#pragma unroll
        for (int ni = 0; ni < 4; ni++) {
            const int ctile = wn + ni * 16 + m16;
            const float bv = bp[cb0 + ctile];
            const int col = n0 + ctile;
#pragma unroll
            for (int r = 0; r < 4; r++) {
                const int row = m0 + wm + mi * 16 + quad * 4 + r;
                float v = acc[mi][ni][r] + bv;
                if (ACT == 1) v = tanhf(v);
                C[(size_t)row * Ncols + col] = v;
            }
        }
    }
}

// ---------------------------------------------------------------------------
// E1: rki = softmax_M(-(ln_r - tab)^2); q = sum rki*h_hat; reset[:,512+u]=f16(q)
// ln_ru is [B, 8192]; r-part is cols 0..4095
// ---------------------------------------------------------------------------
__global__ __launch_bounds__(256) void gate_r_kernel(
    const float* __restrict__ ln_ru, const float* __restrict__ state,
    __half* __restrict__ reset)
{
    const int idx = blockIdx.x * 256 + threadIdx.x;
    const int b = idx >> 9;
    const int u = idx & 511;

    const float TAB[8] = {0.0f, 1.15129254649702f, 2.30258509299405f,
                          3.45387763949107f, 4.60517018598809f, 5.75646273248511f,
                          6.90775527898214f, 8.05904782547916f};

    const float4* xr = (const float4*)(ln_ru + ((size_t)b * NRU2 + u * 8));
    const float4* hh = (const float4*)(state + ((size_t)b * NRU + u * 8));
    float4 x0 = xr[0], x1 = xr[1];
    float4 h0 = hh[0], h1 = hh[1];
    float x[8] = {x0.x, x0.y, x0.z, x0.w, x1.x, x1.y, x1.z, x1.w};
    float h[8] = {h0.x, h0.y, h0.z, h0.w, h1.x, h1.y, h1.z, h1.w};

    float s[8];
    float mx = -1e30f;
#pragma unroll
    for (int i = 0; i < 8; i++) {
        float d = x[i] - TAB[i];
        s[i] = -d * d;
        mx = fmaxf(mx, s[i]);
    }
    float sum = 0.f, qn = 0.f;
#pragma unroll
    for (int i = 0; i < 8; i++) {
        float e = expf(s[i] - mx);
        sum += e;
        qn += e * h[i];
    }
    float q = qn / sum;
    reset[(size_t)b * FD + D_IN + u] = __float2half(q);
}

// ---------------------------------------------------------------------------
// E2: ski softmax; exp decay; h_hat_next; h_next.  u-part is cols 4096..8191
// ---------------------------------------------------------------------------
__global__ __launch_bounds__(256) void final_kernel(
    const float* __restrict__ ln_ru, const float* __restrict__ state,
    const float* __restrict__ qk, const float* __restrict__ elapsed,
    float* __restrict__ out0, float* __restrict__ out1)
{
    const int idx = blockIdx.x * 256 + threadIdx.x;
    const int b = idx >> 9;
    const int u = idx & 511;

    const float TAB[8] = {0.0f, 1.15129254649702f, 2.30258509299405f,
                          3.45387763949107f, 4.60517018598809f, 5.75646273248511f,
                          6.90775527898214f, 8.05904782547916f};
    const float INV_TAU[8] = {1.0f, 0.316227766016838f, 0.1f, 0.0316227766016838f,
                              0.01f, 0.00316227766016838f, 0.001f, 0.000316227766016838f};

    const float4* xr = (const float4*)(ln_ru + ((size_t)b * NRU2 + 4096 + u * 8));
    const float4* hh = (const float4*)(state + ((size_t)b * NRU + u * 8));
    float4 x0 = xr[0], x1 = xr[1];
    float4 h0 = hh[0], h1 = hh[1];
    float x[8] = {x0.x, x0.y, x0.z, x0.w, x1.x, x1.y, x1.z, x1.w};
    float h[8] = {h0.x, h0.y, h0.z, h0.w, h1.x, h1.y, h1.z, h1.w};

    const float q  = qk[(size_t)b * U_N + u];
    const float el = elapsed[b];

    float s[8];
    float mx = -1e30f;
#pragma unroll
    for (int i = 0; i < 8; i++) {
        float d = x[i] - TAB[i];
        s[i] = -d * d;
        mx = fmaxf(mx, s[i]);
    }
    float e[8];
    float sum = 0.f;
#pragma unroll
    for (int i = 0; i < 8; i++) {
        e[i] = expf(s[i] - mx);
        sum += e[i];
    }
    const float inv_sum = 1.0f / sum;

    float hn[8];
    float acc = 0.f;
#pragma unroll
    for (int i = 0; i < 8; i++) {
        float sk = e[i] * inv_sum;
        float et = expf(-el * INV_TAU[i]);
        hn[i] = ((1.0f - sk) * h[i] + sk * q) * et;
        acc += hn[i];
    }

    float4* o = (float4*)(out1 + ((size_t)b * NRU + u * 8));
    o[0] = make_float4(hn[0], hn[1], hn[2], hn[3]);
    o[1] = make_float4(hn[4], hn[5], hn[6], hn[7]);
    out0[(size_t)b * U_N + u] = acc;
}

// ---------------------------------------------------------------------------
extern "C" void kernel_launch(void* const* d_in, const int* in_sizes, int n_in,
                              void* d_out, int out_size, void* d_ws, size_t ws_size,
                              hipStream_t stream)
{
    (void)in_sizes; (void)n_in; (void)out_size; (void)ws_size;

    const float* inputs  = (const float*)d_in[0];
    const float* elapsed = (const float*)d_in[1];
    const float* state   = (const float*)d_in[2];
    const float* W_r     = (const float*)d_in[3];
    const float* b_r     = (const float*)d_in[4];
    const float* W_d     = (const float*)d_in[5];
    const float* b_d     = (const float*)d_in[6];
    const float* W_u     = (const float*)d_in[7];
    const float* b_u     = (const float*)d_in[8];
    float* out = (float*)d_out;

    char* ws = (char*)d_ws;
    __half* fused = (__half*)(ws);                         //  4 MB [2048,1024]
    __half* reset = (__half*)(ws + ((size_t)4  << 20));    //  4 MB [2048,1024]
    __half* WruT  = (__half*)(ws + ((size_t)8  << 20));    // 16 MB [8192,1024]
    __half* WdT   = (__half*)(ws + ((size_t)24 << 20));    //  1 MB [512,1024]
    float*  ln_ru = (float*) (ws + ((size_t)25 << 20));    // 64 MB [2048,8192]
    float*  qk    = (float*) (ws + ((size_t)89 << 20));    //  4 MB [2048,512]

    prep_kernel<<<B_SZ, 256, 0, stream>>>(inputs, state, fused, reset);
    convT_kernel<<<dim3(NRU / 32, FD / 32), 256, 0, stream>>>(W_r, WruT, FD, NRU);
    convT_kernel<<<dim3(NRU / 32, FD / 32), 256, 0, stream>>>(W_u, WruT + (size_t)NRU * FD, FD, NRU);
    convT_kernel<<<dim3(U_N / 32, FD / 32), 256, 0, stream>>>(W_d, WdT, FD, U_N);

    // combined r+u GEMM: [2048,1024] x [8192,1024]^T -> [2048,8192]
    gemm_lds<128, 0><<<dim3(NRU2 / 128, B_SZ / 128), 256, 0, stream>>>(
        fused, WruT, b_r, b_u, NRU, ln_ru, NRU2, FD);

    gate_r_kernel<<<(B_SZ * U_N) / 256, 256, 0, stream>>>(ln_ru, state, reset);

    // detect GEMM: [2048,1024] x [512,1024]^T -> [2048,512], tanh epilogue
    gemm_lds<64, 1><<<dim3(U_N / 128, B_SZ / 64), 256, 0, stream>>>(
        reset, WdT, b_d, b_d, 1 << 30, qk, U_N, FD);

    final_kernel<<<(B_SZ * U_N) / 256, 256, 0, stream>>>(ln_ru, state, qk, elapsed, out,
                                                         out + (size_t)B_SZ * U_N);
}

// Round 3
// 231.236 us; speedup vs baseline: 1.0813x; 1.0073x over previous
//
#include <hip/hip_runtime.h>
#include <hip/hip_fp16.h>
#include <cmath>

#define B_SZ 2048
#define D_IN 512
#define U_N  512
#define FD   1024   // D_IN + U_N
#define NRU  4096   // U_N * M_B
#define NRU2 8192   // combined r+u output cols

typedef _Float16 f16x8 __attribute__((ext_vector_type(8)));
typedef float    f32x4 __attribute__((ext_vector_type(4)));

typedef const __attribute__((address_space(1))) void glb_cv;
typedef __attribute__((address_space(3))) void lds_v;

#define TAB_INIT {0.0f, 1.15129254649702f, 2.30258509299405f, \
                  3.45387763949107f, 4.60517018598809f, 5.75646273248511f, \
                  6.90775527898214f, 8.05904782547916f}

// ---------------------------------------------------------------------------
// P1: h = sum_m state[b,u,m]; fused = [f16(inputs), f16(h)]; reset[:,0:512]=f16(inputs)
// ---------------------------------------------------------------------------
__global__ __launch_bounds__(256) void prep_kernel(
    const float* __restrict__ inputs, const float* __restrict__ state,
    __half* __restrict__ fused, __half* __restrict__ reset)
{
    const int b = blockIdx.x;
    const int t = threadIdx.x;

    const float2 iv = *(const float2*)(inputs + (size_t)b * D_IN + t * 2);
    __half2 hv;
    hv.x = __float2half(iv.x);
    hv.y = __float2half(iv.y);
    *(__half2*)(fused + (size_t)b * FD + t * 2) = hv;
    *(__half2*)(reset + (size_t)b * FD + t * 2) = hv;

    const float4* sp = (const float4*)(state + (size_t)b * NRU + t * 16);
    float4 x0 = sp[0], x1 = sp[1], x2 = sp[2], x3 = sp[3];
    float s0 = (x0.x + x0.y) + (x0.z + x0.w) + (x1.x + x1.y) + (x1.z + x1.w);
    float s1 = (x2.x + x2.y) + (x2.z + x2.w) + (x3.x + x3.y) + (x3.z + x3.w);
    __half2 h2;
    h2.x = __float2half(s0);
    h2.y = __float2half(s1);
    *(__half2*)(fused + (size_t)b * FD + D_IN + t * 2) = h2;
}

// ---------------------------------------------------------------------------
// P2 (merged): transpose-convert W_r, W_u, W_d in one launch.
// grid (272, 32): x<128 -> W_r, x<256 -> W_u, else W_d.  K = FD = 1024.
// ---------------------------------------------------------------------------
__global__ __launch_bounds__(256) void convT3_kernel(
    const float* __restrict__ W_r, const float* __restrict__ W_u,
    const float* __restrict__ W_d, __half* __restrict__ WruT,
    __half* __restrict__ WdT)
{
    __shared__ float tile[32][33];
    const int bx = blockIdx.x;
    const float* W;
    __half* Wt;
    int N, nt;
    if (bx < 128)      { W = W_r; Wt = WruT;                        N = NRU; nt = bx * 32; }
    else if (bx < 256) { W = W_u; Wt = WruT + (size_t)NRU * FD;     N = NRU; nt = (bx - 128) * 32; }
    else               { W = W_d; Wt = WdT;                         N = U_N; nt = (bx - 256) * 32; }

    const int kt = blockIdx.y * 32;
    const int t  = threadIdx.x;
    const int c  = t & 31;
    const int r4 = t >> 5;

#pragma unroll
    for (int i = 0; i < 4; i++) {
        int r = r4 + i * 8;
        tile[r][c] = W[(size_t)(kt + r) * N + nt + c];
    }
    __syncthreads();
#pragma unroll
    for (int i = 0; i < 4; i++) {
        int rr = r4 + i * 8;
        Wt[(size_t)(nt + rr) * FD + kt + c] = __float2half(tile[c][rr]);
    }
}

// ---------------------------------------------------------------------------
// GEMM: [M,K](f16) @ [N,K](f16)^T, BMx128 tile, BK=32, m97-style
// global_load_lds width-16 staging, unpadded [rows][32] LDS.
// EPI=0: C[row][col] = acc + bias (opt tanh).  (detect path)
// EPI=1: fused CTGRU gate epilogue (BM must be 128):
//   n0 < nsplit (r-cols): softmax(-(ln-tab)^2), q = sum rki*h_hat -> reset f16
//   n0 >= nsplit (u-cols): ski softmax -> skibuf f16
// ---------------------------------------------------------------------------
template <int BM, int ACT, int EPI>
__global__ __launch_bounds__(256) void gemm_k(
    const __half* __restrict__ A, const __half* __restrict__ Bt,
    const float* __restrict__ biasA, const float* __restrict__ biasB, int nsplit,
    float* __restrict__ C, int Ncols,
    const float* __restrict__ state, __half* __restrict__ resetw,
    __half* __restrict__ skibuf, int K)
{
    extern __shared__ __align__(16) char smem[];
    __half* sA = (__half*)smem;               // [BM][32]
    __half* sB = (__half*)(smem + BM * 64);   // [128][32]

    const int t    = threadIdx.x;
    const int m0   = blockIdx.y * BM;
    const int n0   = blockIdx.x << 7;
    const int lane = t & 63;
    const int w    = t >> 6;
    const int m16  = lane & 15;
    const int quad = lane >> 4;
    constexpr int MI = BM / 32;
    constexpr int IA = BM / 64;
    const int wm = (w & 1) * (BM / 2);
    const int wn = (w >> 1) << 6;

    f32x4 acc[MI][4];
#pragma unroll
    for (int i = 0; i < MI; i++)
#pragma unroll
        for (int j = 0; j < 4; j++)
#pragma unroll
            for (int r = 0; r < 4; r++) acc[i][j][r] = 0.f;

    const __half* gAp[IA];
    const __half* lAp[IA];
#pragma unroll
    for (int i = 0; i < IA; i++) {
        const int off = w * (BM * 16) + i * 1024 + lane * 16;  // byte off in tile
        const int row = off >> 6;
        const int kc  = (off & 63) >> 1;
        gAp[i] = A + (size_t)(m0 + row) * K + kc;
        lAp[i] = sA + ((w * (BM * 16) + i * 1024) >> 1);
    }
    const __half* gBp[2];
    const __half* lBp[2];
#pragma unroll
    for (int i = 0; i < 2; i++) {
        const int off = w * 2048 + i * 1024 + lane * 16;
        const int row = off >> 6;
        const int kc  = (off & 63) >> 1;
        gBp[i] = Bt + (size_t)(n0 + row) * K + kc;
        lBp[i] = sB + ((w * 2048 + i * 1024) >> 1);
    }

    for (int kt = 0; kt < K; kt += 32) {
        __syncthreads();
#pragma unroll
        for (int i = 0; i < IA; i++)
            __builtin_amdgcn_global_load_lds((glb_cv*)(gAp[i] + kt), (lds_v*)lAp[i], 16, 0, 0);
#pragma unroll
        for (int i = 0; i < 2; i++)
            __builtin_amdgcn_global_load_lds((glb_cv*)(gBp[i] + kt), (lds_v*)lBp[i], 16, 0, 0);
        __syncthreads();

        f16x8 af[MI], bf[4];
#pragma unroll
        for (int mi = 0; mi < MI; mi++)
            af[mi] = *(const f16x8*)(sA + (wm + mi * 16 + m16) * 32 + quad * 8);
#pragma unroll
        for (int ni = 0; ni < 4; ni++)
            bf[ni] = *(const f16x8*)(sB + (wn + ni * 16 + m16) * 32 + quad * 8);
#pragma unroll
        for (int mi = 0; mi < MI; mi++)
#pragma unroll
            for (int ni = 0; ni < 4; ni++)
                acc[mi][ni] = __builtin_amdgcn_mfma_f32_16x16x32_f16(
                    af[mi], bf[ni], acc[mi][ni], 0, 0, 0);
    }

    if constexpr (EPI == 0) {
        const float* bp  = (n0 < nsplit) ? biasA : biasB;
        const int    cb0 = (n0 < nsplit) ? n0 : n0 - nsplit;
#pragma unroll
        for (int mi = 0; mi < MI; mi++) {
#pragma unroll
            for (int ni = 0; ni < 4; ni++) {
                const int ctile = wn + ni * 16 + m16;
                const float bv = bp[cb0 + ctile];
                const int col = n0 + ctile;
#pragma unroll
                for (int r = 0; r < 4; r++) {
                    const int row = m0 + wm + mi * 16 + quad * 4 + r;
                    float v = acc[mi][ni][r] + bv;
                    if (ACT == 1) v = tanhf(v);
                    C[(size_t)row * Ncols + col] = v;
                }
            }
        }
    } else {
        // -------- fused CTGRU gate epilogue (BM == 128) --------
        __syncthreads();   // everyone done reading sA/sB; reuse as scratch
        float* ebuf = (float*)smem + w * (64 * 17);   // per-wave [64][17]
        const bool is_r = (n0 < nsplit);
        const float* bp = is_r ? biasA : biasB;
        const int cb = (is_r ? n0 : n0 - nsplit) + wn;  // col base in r/u space
        const float TAB[8] = TAB_INIT;

        for (int ni = 0; ni < 4; ni++) {
            const float bv = bp[cb + ni * 16 + m16];
#pragma unroll
            for (int mi = 0; mi < 4; mi++)
#pragma unroll
                for (int r = 0; r < 4; r++)
                    ebuf[(mi * 16 + quad * 4 + r) * 17 + m16] = acc[mi][ni][r] + bv;
            __syncthreads();

            const int b = m0 + wm + lane;
#pragma unroll
            for (int j = 0; j < 2; j++) {
                const float* rowp = ebuf + lane * 17 + j * 8;
                float s[8], e[8];
                float mx = -1e30f;
#pragma unroll
                for (int i = 0; i < 8; i++) {
                    float d = rowp[i] - TAB[i];
                    s[i] = -d * d;
                    mx = fmaxf(mx, s[i]);
                }
                float sum = 0.f;
#pragma unroll
                for (int i = 0; i < 8; i++) {
                    e[i] = __expf(s[i] - mx);
                    sum += e[i];
                }
                const int c0 = cb + ni * 16 + j * 8;   // = u*8 in r/u space
                if (is_r) {
                    const float4* hh = (const float4*)(state + (size_t)b * NRU + c0);
                    float4 h0 = hh[0], h1 = hh[1];
                    float hv[8] = {h0.x, h0.y, h0.z, h0.w, h1.x, h1.y, h1.z, h1.w};
                    float qn = 0.f;
#pragma unroll
                    for (int i = 0; i < 8; i++) qn += e[i] * hv[i];
                    const float q = qn / sum;
                    resetw[(size_t)b * FD + D_IN + (c0 >> 3)] = __float2half(q);
                } else {
                    const float inv = 1.0f / sum;
                    __half2 o[4];
#pragma unroll
                    for (int i = 0; i < 4; i++) {
                        o[i].x = __float2half(e[2 * i] * inv);
                        o[i].y = __float2half(e[2 * i + 1] * inv);
                    }
                    *(uint4*)(skibuf + (size_t)b * NRU + c0) = *(uint4*)o;
                }
            }
            __syncthreads();
        }
    }
}

// ---------------------------------------------------------------------------
// E2: h_hat_next = ((1-ski)*h_hat + ski*qk) * exp(-el/tau); h_next = sum_m
// ---------------------------------------------------------------------------
__global__ __launch_bounds__(256) void final_kernel(
    const __half* __restrict__ skibuf, const float* __restrict__ state,
    const float* __restrict__ qk, const float* __restrict__ elapsed,
    float* __restrict__ out0, float* __restrict__ out1)
{
    const int idx = blockIdx.x * 256 + threadIdx.x;
    const int b = idx >> 9;
    const int u = idx & 511;

    const float INV_TAU[8] = {1.0f, 0.316227766016838f, 0.1f, 0.0316227766016838f,
                              0.01f, 0.00316227766016838f, 0.001f, 0.000316227766016838f};

    const uint4 sr = *(const uint4*)(skibuf + (size_t)b * NRU + u * 8);
    const __half2* sh = (const __half2*)&sr;
    float sk[8];
#pragma unroll
    for (int i = 0; i < 4; i++) {
        sk[2 * i]     = __half2float(sh[i].x);
        sk[2 * i + 1] = __half2float(sh[i].y);
    }

    const float4* hh = (const float4*)(state + ((size_t)b * NRU + u * 8));
    float4 h0 = hh[0], h1 = hh[1];
    float h[8] = {h0.x, h0.y, h0.z, h0.w, h1.x, h1.y, h1.z, h1.w};

    const float q  = qk[(size_t)b * U_N + u];
    const float el = elapsed[b];

    float hn[8];
    float acc = 0.f;
#pragma unroll
    for (int i = 0; i < 8; i++) {
        const float et = __expf(-el * INV_TAU[i]);
        hn[i] = ((1.0f - sk[i]) * h[i] + sk[i] * q) * et;
        acc += hn[i];
    }

    float4* o = (float4*)(out1 + ((size_t)b * NRU + u * 8));
    o[0] = make_float4(hn[0], hn[1], hn[2], hn[3]);
    o[1] = make_float4(hn[4], hn[5], hn[6], hn[7]);
    out0[(size_t)b * U_N + u] = acc;
}

// ---------------------------------------------------------------------------
extern "C" void kernel_launch(void* const* d_in, const int* in_sizes, int n_in,
                              void* d_out, int out_size, void* d_ws, size_t ws_size,
                              hipStream_t stream)
{
    (void)in_sizes; (void)n_in; (void)out_size; (void)ws_size;

    const float* inputs  = (const float*)d_in[0];
    const float* elapsed = (const float*)d_in[1];
    const float* state   = (const float*)d_in[2];
    const float* W_r     = (const float*)d_in[3];
    const float* b_r     = (const float*)d_in[4];
    const float* W_d     = (const float*)d_in[5];
    const float* b_d     = (const float*)d_in[6];
    const float* W_u     = (const float*)d_in[7];
    const float* b_u     = (const float*)d_in[8];
    float* out = (float*)d_out;

    char* ws = (char*)d_ws;
    __half* fused  = (__half*)(ws);                         //  4 MB [2048,1024]
    __half* reset  = (__half*)(ws + ((size_t)4  << 20));    //  4 MB [2048,1024]
    __half* WruT   = (__half*)(ws + ((size_t)8  << 20));    // 16 MB [8192,1024]
    __half* WdT    = (__half*)(ws + ((size_t)24 << 20));    //  1 MB [512,1024]
    __half* skibuf = (__half*)(ws + ((size_t)25 << 20));    // 16 MB [2048,4096]
    float*  qk     = (float*) (ws + ((size_t)41 << 20));    //  4 MB [2048,512]

    prep_kernel<<<B_SZ, 256, 0, stream>>>(inputs, state, fused, reset);
    convT3_kernel<<<dim3(272, FD / 32), 256, 0, stream>>>(W_r, W_u, W_d, WruT, WdT);

    // combined r+u GEMM with fused gate epilogue: [2048,1024] x [8192,1024]^T
    gemm_k<128, 0, 1><<<dim3(NRU2 / 128, B_SZ / 128), 256, 17408, stream>>>(
        fused, WruT, b_r, b_u, NRU, nullptr, 0, state, reset, skibuf, FD);

    // detect GEMM: [2048,1024] x [512,1024]^T -> qk fp32, tanh epilogue
    gemm_k<64, 1, 0><<<dim3(U_N / 128, B_SZ / 64), 256, 12288, stream>>>(
        reset, WdT, b_d, b_d, 1 << 30, qk, U_N, nullptr, nullptr, nullptr, FD);

    final_kernel<<<(B_SZ * U_N) / 256, 256, 0, stream>>>(skibuf, state, qk, elapsed, out,
                                                         out + (size_t)B_SZ * U_N);
}

// Round 4
// 225.845 us; speedup vs baseline: 1.1071x; 1.0239x over previous
//
#include <hip/hip_runtime.h>
#include <hip/hip_fp16.h>
#include <cmath>

#define B_SZ 2048
#define D_IN 512
#define U_N  512
#define FD   1024   // D_IN + U_N
#define NRU  4096   // U_N * M_B
#define NRU2 8192   // combined r+u output cols

typedef _Float16 f16x8 __attribute__((ext_vector_type(8)));
typedef float    f32x4 __attribute__((ext_vector_type(4)));

typedef const __attribute__((address_space(1))) void glb_cv;
typedef __attribute__((address_space(3))) void lds_v;

#define TAB_INIT {0.0f, 1.15129254649702f, 2.30258509299405f, \
                  3.45387763949107f, 4.60517018598809f, 5.75646273248511f, \
                  6.90775527898214f, 8.05904782547916f}

// ---------------------------------------------------------------------------
// P1: h = sum_m state[b,u,m]; fused = [f16(inputs), f16(h)]; reset[:,0:512]=f16(inputs)
// ---------------------------------------------------------------------------
__global__ __launch_bounds__(256) void prep_kernel(
    const float* __restrict__ inputs, const float* __restrict__ state,
    __half* __restrict__ fused, __half* __restrict__ reset)
{
    const int b = blockIdx.x;
    const int t = threadIdx.x;

    const float2 iv = *(const float2*)(inputs + (size_t)b * D_IN + t * 2);
    __half2 hv;
    hv.x = __float2half(iv.x);
    hv.y = __float2half(iv.y);
    *(__half2*)(fused + (size_t)b * FD + t * 2) = hv;
    *(__half2*)(reset + (size_t)b * FD + t * 2) = hv;

    const float4* sp = (const float4*)(state + (size_t)b * NRU + t * 16);
    float4 x0 = sp[0], x1 = sp[1], x2 = sp[2], x3 = sp[3];
    float s0 = (x0.x + x0.y) + (x0.z + x0.w) + (x1.x + x1.y) + (x1.z + x1.w);
    float s1 = (x2.x + x2.y) + (x2.z + x2.w) + (x3.x + x3.y) + (x3.z + x3.w);
    __half2 h2;
    h2.x = __float2half(s0);
    h2.y = __float2half(s1);
    *(__half2*)(fused + (size_t)b * FD + D_IN + t * 2) = h2;
}

// ---------------------------------------------------------------------------
// P2 (merged): transpose-convert W_r, W_u, W_d in one launch.
// ---------------------------------------------------------------------------
__global__ __launch_bounds__(256) void convT3_kernel(
    const float* __restrict__ W_r, const float* __restrict__ W_u,
    const float* __restrict__ W_d, __half* __restrict__ WruT,
    __half* __restrict__ WdT)
{
    __shared__ float tile[32][33];
    const int bx = blockIdx.x;
    const float* W;
    __half* Wt;
    int N, nt;
    if (bx < 128)      { W = W_r; Wt = WruT;                    N = NRU; nt = bx * 32; }
    else if (bx < 256) { W = W_u; Wt = WruT + (size_t)NRU * FD; N = NRU; nt = (bx - 128) * 32; }
    else               { W = W_d; Wt = WdT;                     N = U_N; nt = (bx - 256) * 32; }

    const int kt = blockIdx.y * 32;
    const int t  = threadIdx.x;
    const int c  = t & 31;
    const int r4 = t >> 5;

#pragma unroll
    for (int i = 0; i < 4; i++) {
        int r = r4 + i * 8;
        tile[r][c] = W[(size_t)(kt + r) * N + nt + c];
    }
    __syncthreads();
#pragma unroll
    for (int i = 0; i < 4; i++) {
        int rr = r4 + i * 8;
        Wt[(size_t)(nt + rr) * FD + kt + c] = __float2half(tile[c][rr]);
    }
}

// ---------------------------------------------------------------------------
// GEMM: [M,K](f16) @ [N,K](f16)^T, BMx128 tile, BK=32, m97-style
// global_load_lds width-16 staging, unpadded [rows][32] LDS.
// EPI=1 (BM=128): fused CTGRU gate epilogue, coalesced mapping:
//   r-cols: softmax(-(ln-tab)^2), q = sum rki*h_hat -> reset f16 (via qbuf)
//   u-cols: ski softmax -> skibuf f16
// EPI=2 (BM=64): detect GEMM (tanh) + fused final: reads skibuf/state/elapsed,
//   writes h_next (out0) and h_hat_next (out1).
// ---------------------------------------------------------------------------
template <int BM, int EPI>
__global__ __launch_bounds__(256) void gemm_k(
    const __half* __restrict__ A, const __half* __restrict__ Bt,
    const float* __restrict__ biasA, const float* __restrict__ biasB, int nsplit,
    const float* __restrict__ state, __half* __restrict__ resetw,
    __half* __restrict__ skibuf, const float* __restrict__ elapsed,
    float* __restrict__ out0, float* __restrict__ out1, int K)
{
    extern __shared__ __align__(16) char smem[];
    __half* sA = (__half*)smem;               // [BM][32]
    __half* sB = (__half*)(smem + BM * 64);   // [128][32]

    const int t    = threadIdx.x;
    const int m0   = blockIdx.y * BM;
    const int n0   = blockIdx.x << 7;
    const int lane = t & 63;
    const int w    = t >> 6;
    const int m16  = lane & 15;
    const int quad = lane >> 4;
    constexpr int MI = BM / 32;
    constexpr int IA = BM / 64;
    const int wm = (w & 1) * (BM / 2);
    const int wn = (w >> 1) << 6;
    const int strip = w >> 1;

    f32x4 acc[MI][4];
#pragma unroll
    for (int i = 0; i < MI; i++)
#pragma unroll
        for (int j = 0; j < 4; j++)
#pragma unroll
            for (int r = 0; r < 4; r++) acc[i][j][r] = 0.f;

    const __half* gAp[IA];
    const __half* lAp[IA];
#pragma unroll
    for (int i = 0; i < IA; i++) {
        const int off = w * (BM * 16) + i * 1024 + lane * 16;  // byte off in tile
        const int row = off >> 6;
        const int kc  = (off & 63) >> 1;
        gAp[i] = A + (size_t)(m0 + row) * K + kc;
        lAp[i] = sA + ((w * (BM * 16) + i * 1024) >> 1);
    }
    const __half* gBp[2];
    const __half* lBp[2];
#pragma unroll
    for (int i = 0; i < 2; i++) {
        const int off = w * 2048 + i * 1024 + lane * 16;
        const int row = off >> 6;
        const int kc  = (off & 63) >> 1;
        gBp[i] = Bt + (size_t)(n0 + row) * K + kc;
        lBp[i] = sB + ((w * 2048 + i * 1024) >> 1);
    }

    for (int kt = 0; kt < K; kt += 32) {
        __syncthreads();
#pragma unroll
        for (int i = 0; i < IA; i++)
            __builtin_amdgcn_global_load_lds((glb_cv*)(gAp[i] + kt), (lds_v*)lAp[i], 16, 0, 0);
#pragma unroll
        for (int i = 0; i < 2; i++)
            __builtin_amdgcn_global_load_lds((glb_cv*)(gBp[i] + kt), (lds_v*)lBp[i], 16, 0, 0);
        __syncthreads();

        f16x8 af[MI], bf[4];
#pragma unroll
        for (int mi = 0; mi < MI; mi++)
            af[mi] = *(const f16x8*)(sA + (wm + mi * 16 + m16) * 32 + quad * 8);
#pragma unroll
        for (int ni = 0; ni < 4; ni++)
            bf[ni] = *(const f16x8*)(sB + (wn + ni * 16 + m16) * 32 + quad * 8);
#pragma unroll
        for (int mi = 0; mi < MI; mi++)
#pragma unroll
            for (int ni = 0; ni < 4; ni++)
                acc[mi][ni] = __builtin_amdgcn_mfma_f32_16x16x32_f16(
                    af[mi], bf[ni], acc[mi][ni], 0, 0, 0);
    }

    if constexpr (EPI == 1) {
        // -------- fused gate epilogue, coalesced (BM == 128) --------
        __syncthreads();
        float*  ebuf = (float*)smem;                    // [128][36]
        __half* qbuf = (__half*)(smem + 128 * 36 * 4);  // [128][16]
        const bool is_r = (n0 < nsplit);
        const float* bp = is_r ? biasA : biasB;
        const int n0r = is_r ? n0 : n0 - nsplit;   // col base in r/u space
        const float TAB[8] = TAB_INIT;
        const int ug  = t & 3;         // 0,1: strip0 groups; 2,3: strip1 groups
        const int s   = ug >> 1;
        const int g   = ug & 1;
        const int bl0 = t >> 2;        // 0..63

        for (int ni = 0; ni < 4; ni++) {
            const float bv = bp[n0r + strip * 64 + ni * 16 + m16];
#pragma unroll
            for (int mi = 0; mi < 4; mi++)
#pragma unroll
                for (int r = 0; r < 4; r++)
                    ebuf[(wm + mi * 16 + quad * 4 + r) * 36 + strip * 16 + m16] =
                        acc[mi][ni][r] + bv;
            __syncthreads();

#pragma unroll
            for (int p = 0; p < 2; p++) {
                const int b_loc = bl0 + p * 64;
                const int b = m0 + b_loc;
                const float* rowp = ebuf + b_loc * 36 + ug * 8;
                float v[8];
                *(float4*)&v[0] = *(const float4*)rowp;
                *(float4*)&v[4] = *(const float4*)(rowp + 4);

                float sc[8], e[8];
                float mx = -1e30f;
#pragma unroll
                for (int i = 0; i < 8; i++) {
                    float d = v[i] - TAB[i];
                    sc[i] = -d * d;
                    mx = fmaxf(mx, sc[i]);
                }
                float sum = 0.f;
#pragma unroll
                for (int i = 0; i < 8; i++) {
                    e[i] = __expf(sc[i] - mx);
                    sum += e[i];
                }
                const int col = n0r + s * 64 + ni * 16 + g * 8;  // flat (u*8) col
                if (is_r) {
                    const float4 h0 = *(const float4*)(state + (size_t)b * NRU + col);
                    const float4 h1 = *(const float4*)(state + (size_t)b * NRU + col + 4);
                    const float hv[8] = {h0.x, h0.y, h0.z, h0.w, h1.x, h1.y, h1.z, h1.w};
                    float qn = 0.f;
#pragma unroll
                    for (int i = 0; i < 8; i++) qn += e[i] * hv[i];
                    qbuf[b_loc * 16 + (s * 8 + ni * 2 + g)] = __float2half(qn / sum);
                } else {
                    const float inv = 1.0f / sum;
                    __half2 o[4];
#pragma unroll
                    for (int i = 0; i < 4; i++) {
                        o[i].x = __float2half(e[2 * i] * inv);
                        o[i].y = __float2half(e[2 * i + 1] * inv);
                    }
                    *(uint4*)(skibuf + (size_t)b * NRU + col) = *(uint4*)o;
                }
            }
            __syncthreads();
        }
        if (is_r) {
            // coalesced q write-out: 16 contiguous u's per block
            const int b_loc = t >> 1;
            const int j = t & 1;
            uint4 qv = *(uint4*)(qbuf + b_loc * 16 + j * 8);
            *(uint4*)(resetw + (size_t)(m0 + b_loc) * FD + D_IN + (n0r >> 3) + j * 8) = qv;
        }
    } else {
        // -------- detect tanh + fused final epilogue (BM == 64) --------
        __syncthreads();
        float* ebuf  = (float*)smem;            // [64][36] = 9216 B
        float* etbuf = (float*)(smem + 9216);   // [64][8] decay table
        const float INV_TAU[8] = {1.0f, 0.316227766016838f, 0.1f, 0.0316227766016838f,
                                  0.01f, 0.00316227766016838f, 0.001f, 0.000316227766016838f};
#pragma unroll
        for (int q2 = 0; q2 < 2; q2++) {
            const int id = t + q2 * 256;
            const int bl = id >> 3, i = id & 7;
            etbuf[bl * 8 + i] = __expf(-elapsed[m0 + bl] * INV_TAU[i]);
        }
        const int ul  = t & 31;   // 0..31 units per ni chunk
        const int bl0 = t >> 5;   // 0..7

        for (int ni = 0; ni < 4; ni++) {
            const float bv = biasA[n0 + strip * 64 + ni * 16 + m16];
#pragma unroll
            for (int mi = 0; mi < MI; mi++)
#pragma unroll
                for (int r = 0; r < 4; r++)
                    ebuf[(wm + mi * 16 + quad * 4 + r) * 36 + strip * 16 + m16] =
                        tanhf(acc[mi][ni][r] + bv);
            __syncthreads();

#pragma unroll
            for (int p = 0; p < 8; p++) {
                const int b_loc = bl0 + p * 8;
                const int b = m0 + b_loc;
                const float qv = ebuf[b_loc * 36 + ul];
                const int u = n0 + (ul >> 4) * 64 + ni * 16 + (ul & 15);  // unit idx

                const uint4 sr = *(const uint4*)(skibuf + (size_t)b * NRU + u * 8);
                const float4 h0 = *(const float4*)(state + (size_t)b * NRU + u * 8);
                const float4 h1 = *(const float4*)(state + (size_t)b * NRU + u * 8 + 4);
                const float h[8] = {h0.x, h0.y, h0.z, h0.w, h1.x, h1.y, h1.z, h1.w};
                const __half2* sh = (const __half2*)&sr;
                float sk[8];
#pragma unroll
                for (int i = 0; i < 4; i++) {
                    float2 f2 = __half22float2(sh[i]);
                    sk[2 * i] = f2.x;
                    sk[2 * i + 1] = f2.y;
                }
                float hn[8];
                float accs = 0.f;
#pragma unroll
                for (int i = 0; i < 8; i++) {
                    const float et = etbuf[b_loc * 8 + i];
                    hn[i] = ((1.0f - sk[i]) * h[i] + sk[i] * qv) * et;
                    accs += hn[i];
                }
                *(float4*)(out1 + (size_t)b * NRU + u * 8)     = make_float4(hn[0], hn[1], hn[2], hn[3]);
                *(float4*)(out1 + (size_t)b * NRU + u * 8 + 4) = make_float4(hn[4], hn[5], hn[6], hn[7]);
                out0[(size_t)b * U_N + u] = accs;
            }
            __syncthreads();
        }
    }
}

// ---------------------------------------------------------------------------
extern "C" void kernel_launch(void* const* d_in, const int* in_sizes, int n_in,
                              void* d_out, int out_size, void* d_ws, size_t ws_size,
                              hipStream_t stream)
{
    (void)in_sizes; (void)n_in; (void)out_size; (void)ws_size;

    const float* inputs  = (const float*)d_in[0];
    const float* elapsed = (const float*)d_in[1];
    const float* state   = (const float*)d_in[2];
    const float* W_r     = (const float*)d_in[3];
    const float* b_r     = (const float*)d_in[4];
    const float* W_d     = (const float*)d_in[5];
    const float* b_d     = (const float*)d_in[6];
    const float* W_u     = (const float*)d_in[7];
    const float* b_u     = (const float*)d_in[8];
    float* out = (float*)d_out;

    char* ws = (char*)d_ws;
    __half* fused  = (__half*)(ws);                         //  4 MB [2048,1024]
    __half* reset  = (__half*)(ws + ((size_t)4  << 20));    //  4 MB [2048,1024]
    __half* WruT   = (__half*)(ws + ((size_t)8  << 20));    // 16 MB [8192,1024]
    __half* WdT    = (__half*)(ws + ((size_t)24 << 20));    //  1 MB [512,1024]
    __half* skibuf = (__half*)(ws + ((size_t)25 << 20));    // 16 MB [2048,4096]

    prep_kernel<<<B_SZ, 256, 0, stream>>>(inputs, state, fused, reset);
    convT3_kernel<<<dim3(272, FD / 32), 256, 0, stream>>>(W_r, W_u, W_d, WruT, WdT);

    // combined r+u GEMM with fused gate epilogue: [2048,1024] x [8192,1024]^T
    gemm_k<128, 1><<<dim3(NRU2 / 128, B_SZ / 128), 256, 22528, stream>>>(
        fused, WruT, b_r, b_u, NRU, state, reset, skibuf, nullptr, nullptr, nullptr, FD);

    // detect GEMM + fused final: [2048,1024] x [512,1024]^T, tanh, decay, outputs
    gemm_k<64, 2><<<dim3(U_N / 128, B_SZ / 64), 256, 12288, stream>>>(
        reset, WdT, b_d, nullptr, 1 << 30, state, nullptr, skibuf, elapsed,
        out, out + (size_t)B_SZ * U_N, FD);
}

// Round 5
// 222.069 us; speedup vs baseline: 1.1259x; 1.0170x over previous
//
#include <hip/hip_runtime.h>
#include <hip/hip_fp16.h>
#include <cmath>

#define B_SZ 2048
#define D_IN 512
#define U_N  512
#define FD   1024   // D_IN + U_N
#define NRU  4096   // U_N * M_B
#define NRU2 8192   // combined r+u output cols

typedef _Float16 f16x8 __attribute__((ext_vector_type(8)));
typedef float    f32x4 __attribute__((ext_vector_type(4)));

typedef const __attribute__((address_space(1))) void glb_cv;
typedef __attribute__((address_space(3))) void lds_v;

#define TAB_INIT {0.0f, 1.15129254649702f, 2.30258509299405f, \
                  3.45387763949107f, 4.60517018598809f, 5.75646273248511f, \
                  6.90775527898214f, 8.05904782547916f}

// ---------------------------------------------------------------------------
// P1: h = sum_m state[b,u,m]; fused = [f16(inputs), f16(h)]; reset[:,0:512]=f16(inputs)
// ---------------------------------------------------------------------------
__global__ __launch_bounds__(256) void prep_kernel(
    const float* __restrict__ inputs, const float* __restrict__ state,
    __half* __restrict__ fused, __half* __restrict__ reset)
{
    const int b = blockIdx.x;
    const int t = threadIdx.x;

    const float2 iv = *(const float2*)(inputs + (size_t)b * D_IN + t * 2);
    __half2 hv;
    hv.x = __float2half(iv.x);
    hv.y = __float2half(iv.y);
    *(__half2*)(fused + (size_t)b * FD + t * 2) = hv;
    *(__half2*)(reset + (size_t)b * FD + t * 2) = hv;

    const float4* sp = (const float4*)(state + (size_t)b * NRU + t * 16);
    float4 x0 = sp[0], x1 = sp[1], x2 = sp[2], x3 = sp[3];
    float s0 = (x0.x + x0.y) + (x0.z + x0.w) + (x1.x + x1.y) + (x1.z + x1.w);
    float s1 = (x2.x + x2.y) + (x2.z + x2.w) + (x3.x + x3.y) + (x3.z + x3.w);
    __half2 h2;
    h2.x = __float2half(s0);
    h2.y = __float2half(s1);
    *(__half2*)(fused + (size_t)b * FD + D_IN + t * 2) = h2;
}

// ---------------------------------------------------------------------------
// P2 (merged): transpose-convert W_r, W_u, W_d in one launch.
// ---------------------------------------------------------------------------
__global__ __launch_bounds__(256) void convT3_kernel(
    const float* __restrict__ W_r, const float* __restrict__ W_u,
    const float* __restrict__ W_d, __half* __restrict__ WruT,
    __half* __restrict__ WdT)
{
    __shared__ float tile[32][33];
    const int bx = blockIdx.x;
    const float* W;
    __half* Wt;
    int N, nt;
    if (bx < 128)      { W = W_r; Wt = WruT;                    N = NRU; nt = bx * 32; }
    else if (bx < 256) { W = W_u; Wt = WruT + (size_t)NRU * FD; N = NRU; nt = (bx - 128) * 32; }
    else               { W = W_d; Wt = WdT;                     N = U_N; nt = (bx - 256) * 32; }

    const int kt = blockIdx.y * 32;
    const int t  = threadIdx.x;
    const int c  = t & 31;
    const int r4 = t >> 5;

#pragma unroll
    for (int i = 0; i < 4; i++) {
        int r = r4 + i * 8;
        tile[r][c] = W[(size_t)(kt + r) * N + nt + c];
    }
    __syncthreads();
#pragma unroll
    for (int i = 0; i < 4; i++) {
        int rr = r4 + i * 8;
        Wt[(size_t)(nt + rr) * FD + kt + c] = __float2half(tile[c][rr]);
    }
}

// ---------------------------------------------------------------------------
// GEMM: [M,K](f16) @ [N,K](f16)^T, BMx128 tile, BK=64, m97-style
// global_load_lds width-16 staging, unpadded [rows][64] LDS.
// EPI=0 (BM=64): qk[row][col] = tanhf(acc + biasA[col])   (detect path)
// EPI=1 (BM=128): fused CTGRU gate epilogue, coalesced mapping:
//   r-cols: softmax(-(ln-tab)^2), q = sum rki*h_hat -> reset f16 (via qbuf)
//   u-cols: ski softmax -> skibuf f16
// ---------------------------------------------------------------------------
template <int BM, int EPI>
__global__ __launch_bounds__(256) void gemm_k(
    const __half* __restrict__ A, const __half* __restrict__ Bt,
    const float* __restrict__ biasA, const float* __restrict__ biasB, int nsplit,
    float* __restrict__ C, int Ncols,
    const float* __restrict__ state, __half* __restrict__ resetw,
    __half* __restrict__ skibuf, int K)
{
    extern __shared__ __align__(16) char smem[];
    __half* sA = (__half*)smem;                // [BM][64]
    __half* sB = (__half*)(smem + BM * 128);   // [128][64]

    const int t    = threadIdx.x;
    const int m0   = blockIdx.y * BM;
    const int n0   = blockIdx.x << 7;
    const int lane = t & 63;
    const int w    = t >> 6;
    const int m16  = lane & 15;
    const int quad = lane >> 4;
    constexpr int MI = BM / 32;       // m-frags per wave
    constexpr int IA = BM / 32;       // A staging instrs per wave (BM*128B/4/1024)
    const int wm = (w & 1) * (BM / 2);
    const int wn = (w >> 1) << 6;
    const int strip = w >> 1;

    f32x4 acc[MI][4];
#pragma unroll
    for (int i = 0; i < MI; i++)
#pragma unroll
        for (int j = 0; j < 4; j++)
#pragma unroll
            for (int r = 0; r < 4; r++) acc[i][j][r] = 0.f;

    const __half* gAp[IA];
    const __half* lAp[IA];
#pragma unroll
    for (int i = 0; i < IA; i++) {
        const int off = w * (BM * 32) + i * 1024 + lane * 16;  // byte off in tile
        const int row = off >> 7;
        const int kc  = (off & 127) >> 1;
        gAp[i] = A + (size_t)(m0 + row) * K + kc;
        lAp[i] = sA + ((w * (BM * 32) + i * 1024) >> 1);
    }
    const __half* gBp[4];
    const __half* lBp[4];
#pragma unroll
    for (int i = 0; i < 4; i++) {
        const int off = w * 4096 + i * 1024 + lane * 16;
        const int row = off >> 7;
        const int kc  = (off & 127) >> 1;
        gBp[i] = Bt + (size_t)(n0 + row) * K + kc;
        lBp[i] = sB + ((w * 4096 + i * 1024) >> 1);
    }

    for (int kt = 0; kt < K; kt += 64) {
        __syncthreads();
#pragma unroll
        for (int i = 0; i < IA; i++)
            __builtin_amdgcn_global_load_lds((glb_cv*)(gAp[i] + kt), (lds_v*)lAp[i], 16, 0, 0);
#pragma unroll
        for (int i = 0; i < 4; i++)
            __builtin_amdgcn_global_load_lds((glb_cv*)(gBp[i] + kt), (lds_v*)lBp[i], 16, 0, 0);
        __syncthreads();

#pragma unroll
        for (int s = 0; s < 2; s++) {
            f16x8 af[MI], bf[4];
#pragma unroll
            for (int mi = 0; mi < MI; mi++)
                af[mi] = *(const f16x8*)(sA + (wm + mi * 16 + m16) * 64 + s * 32 + quad * 8);
#pragma unroll
            for (int ni = 0; ni < 4; ni++)
                bf[ni] = *(const f16x8*)(sB + (wn + ni * 16 + m16) * 64 + s * 32 + quad * 8);
#pragma unroll
            for (int mi = 0; mi < MI; mi++)
#pragma unroll
                for (int ni = 0; ni < 4; ni++)
                    acc[mi][ni] = __builtin_amdgcn_mfma_f32_16x16x32_f16(
                        af[mi], bf[ni], acc[mi][ni], 0, 0, 0);
        }
    }

    if constexpr (EPI == 0) {
        // -------- detect: tanh + plain store (BM == 64) --------
#pragma unroll
        for (int mi = 0; mi < MI; mi++) {
#pragma unroll
            for (int ni = 0; ni < 4; ni++) {
                const int col = n0 + wn + ni * 16 + m16;
                const float bv = biasA[col];
#pragma unroll
                for (int r = 0; r < 4; r++) {
                    const int row = m0 + wm + mi * 16 + quad * 4 + r;
                    C[(size_t)row * Ncols + col] = tanhf(acc[mi][ni][r] + bv);
                }
            }
        }
    } else {
        // -------- fused gate epilogue, coalesced (BM == 128) --------
        __syncthreads();
        float*  ebuf = (float*)smem;                    // [128][36]
        __half* qbuf = (__half*)(smem + 128 * 36 * 4);  // [128][16]
        const bool is_r = (n0 < nsplit);
        const float* bp = is_r ? biasA : biasB;
        const int n0r = is_r ? n0 : n0 - nsplit;   // col base in r/u space
        const float TAB[8] = TAB_INIT;
        const int ug  = t & 3;
        const int s   = ug >> 1;
        const int g   = ug & 1;
        const int bl0 = t >> 2;        // 0..63

        for (int ni = 0; ni < 4; ni++) {
            const float bv = bp[n0r + strip * 64 + ni * 16 + m16];
#pragma unroll
            for (int mi = 0; mi < 4; mi++)
#pragma unroll
                for (int r = 0; r < 4; r++)
                    ebuf[(wm + mi * 16 + quad * 4 + r) * 36 + strip * 16 + m16] =
                        acc[mi][ni][r] + bv;
            __syncthreads();

#pragma unroll
            for (int p = 0; p < 2; p++) {
                const int b_loc = bl0 + p * 64;
                const int b = m0 + b_loc;
                const float* rowp = ebuf + b_loc * 36 + ug * 8;
                float v[8];
                *(float4*)&v[0] = *(const float4*)rowp;
                *(float4*)&v[4] = *(const float4*)(rowp + 4);

                float e[8];
                float sum = 0.f;
#pragma unroll
                for (int i = 0; i < 8; i++) {
                    float d = v[i] - TAB[i];
                    e[i] = __expf(-d * d);
                    sum += e[i];
                }
                const int col = n0r + s * 64 + ni * 16 + g * 8;  // flat (u*8) col
                if (is_r) {
                    const float4 h0 = *(const float4*)(state + (size_t)b * NRU + col);
                    const float4 h1 = *(const float4*)(state + (size_t)b * NRU + col + 4);
                    const float hv[8] = {h0.x, h0.y, h0.z, h0.w, h1.x, h1.y, h1.z, h1.w};
                    float qn = 0.f;
#pragma unroll
                    for (int i = 0; i < 8; i++) qn += e[i] * hv[i];
                    qbuf[b_loc * 16 + (s * 8 + ni * 2 + g)] = __float2half(qn / sum);
                } else {
                    const float inv = 1.0f / sum;
                    __half2 o[4];
#pragma unroll
                    for (int i = 0; i < 4; i++) {
                        o[i].x = __float2half(e[2 * i] * inv);
                        o[i].y = __float2half(e[2 * i + 1] * inv);
                    }
                    *(uint4*)(skibuf + (size_t)b * NRU + col) = *(uint4*)o;
                }
            }
            __syncthreads();
        }
        if (is_r) {
            const int b_loc = t >> 1;
            const int j = t & 1;
            uint4 qv = *(uint4*)(qbuf + b_loc * 16 + j * 8);
            *(uint4*)(resetw + (size_t)(m0 + b_loc) * FD + D_IN + (n0r >> 3) + j * 8) = qv;
        }
    }
}

// ---------------------------------------------------------------------------
// E2: h_hat_next = ((1-ski)*h_hat + ski*qk) * exp(-el/tau); h_next = sum_m
// ---------------------------------------------------------------------------
__global__ __launch_bounds__(256) void final_kernel(
    const __half* __restrict__ skibuf, const float* __restrict__ state,
    const float* __restrict__ qk, const float* __restrict__ elapsed,
    float* __restrict__ out0, float* __restrict__ out1)
{
    const int idx = blockIdx.x * 256 + threadIdx.x;
    const int b = idx >> 9;
    const int u = idx & 511;

    const float INV_TAU[8] = {1.0f, 0.316227766016838f, 0.1f, 0.0316227766016838f,
                              0.01f, 0.00316227766016838f, 0.001f, 0.000316227766016838f};

    const uint4 sr = *(const uint4*)(skibuf + (size_t)b * NRU + u * 8);
    const __half2* sh = (const __half2*)&sr;
    float sk[8];
#pragma unroll
    for (int i = 0; i < 4; i++) {
        float2 f2 = __half22float2(sh[i]);
        sk[2 * i]     = f2.x;
        sk[2 * i + 1] = f2.y;
    }

    const float4* hh = (const float4*)(state + ((size_t)b * NRU + u * 8));
    float4 h0 = hh[0], h1 = hh[1];
    float h[8] = {h0.x, h0.y, h0.z, h0.w, h1.x, h1.y, h1.z, h1.w};

    const float q  = qk[(size_t)b * U_N + u];
    const float el = elapsed[b];

    float hn[8];
    float acc = 0.f;
#pragma unroll
    for (int i = 0; i < 8; i++) {
        const float et = __expf(-el * INV_TAU[i]);
        hn[i] = ((1.0f - sk[i]) * h[i] + sk[i] * q) * et;
        acc += hn[i];
    }

    float4* o = (float4*)(out1 + ((size_t)b * NRU + u * 8));
    o[0] = make_float4(hn[0], hn[1], hn[2], hn[3]);
    o[1] = make_float4(hn[4], hn[5], hn[6], hn[7]);
    out0[(size_t)b * U_N + u] = acc;
}

// ---------------------------------------------------------------------------
extern "C" void kernel_launch(void* const* d_in, const int* in_sizes, int n_in,
                              void* d_out, int out_size, void* d_ws, size_t ws_size,
                              hipStream_t stream)
{
    (void)in_sizes; (void)n_in; (void)out_size; (void)ws_size;

    const float* inputs  = (const float*)d_in[0];
    const float* elapsed = (const float*)d_in[1];
    const float* state   = (const float*)d_in[2];
    const float* W_r     = (const float*)d_in[3];
    const float* b_r     = (const float*)d_in[4];
    const float* W_d     = (const float*)d_in[5];
    const float* b_d     = (const float*)d_in[6];
    const float* W_u     = (const float*)d_in[7];
    const float* b_u     = (const float*)d_in[8];
    float* out = (float*)d_out;

    char* ws = (char*)d_ws;
    __half* fused  = (__half*)(ws);                         //  4 MB [2048,1024]
    __half* reset  = (__half*)(ws + ((size_t)4  << 20));    //  4 MB [2048,1024]
    __half* WruT   = (__half*)(ws + ((size_t)8  << 20));    // 16 MB [8192,1024]
    __half* WdT    = (__half*)(ws + ((size_t)24 << 20));    //  1 MB [512,1024]
    __half* skibuf = (__half*)(ws + ((size_t)25 << 20));    // 16 MB [2048,4096]
    float*  qk     = (float*) (ws + ((size_t)41 << 20));    //  4 MB [2048,512]

    prep_kernel<<<B_SZ, 256, 0, stream>>>(inputs, state, fused, reset);
    convT3_kernel<<<dim3(272, FD / 32), 256, 0, stream>>>(W_r, W_u, W_d, WruT, WdT);

    // combined r+u GEMM with fused gate epilogue: [2048,1024] x [8192,1024]^T
    gemm_k<128, 1><<<dim3(NRU2 / 128, B_SZ / 128), 256, 32768, stream>>>(
        fused, WruT, b_r, b_u, NRU, nullptr, 0, state, reset, skibuf, FD);

    // detect GEMM: [2048,1024] x [512,1024]^T -> qk fp32 (tanh)
    gemm_k<64, 0><<<dim3(U_N / 128, B_SZ / 64), 256, 24576, stream>>>(
        reset, WdT, b_d, nullptr, 1 << 30, qk, U_N, nullptr, nullptr, nullptr, FD);

    final_kernel<<<(B_SZ * U_N) / 256, 256, 0, stream>>>(skibuf, state, qk, elapsed, out,
                                                         out + (size_t)B_SZ * U_N);
}

// Round 6
// 212.289 us; speedup vs baseline: 1.1778x; 1.0461x over previous
//
#include <hip/hip_runtime.h>
#include <hip/hip_fp16.h>
#include <cmath>

#define B_SZ 2048
#define D_IN 512
#define U_N  512
#define FD   1024   // D_IN + U_N
#define NRU  4096   // U_N * M_B
#define NRU2 8192   // combined r+u output cols

typedef _Float16 f16x8 __attribute__((ext_vector_type(8)));
typedef float    f32x4 __attribute__((ext_vector_type(4)));

typedef const __attribute__((address_space(1))) void glb_cv;
typedef __attribute__((address_space(3))) void lds_v;

#define TAB_INIT {0.0f, 1.15129254649702f, 2.30258509299405f, \
                  3.45387763949107f, 4.60517018598809f, 5.75646273248511f, \
                  6.90775527898214f, 8.05904782547916f}

// ---------------------------------------------------------------------------
// P1: h = sum_m state[b,u,m]; fused = [f16(inputs), f16(h)]; reset[:,0:512]=f16(inputs)
// ---------------------------------------------------------------------------
__global__ __launch_bounds__(256) void prep_kernel(
    const float* __restrict__ inputs, const float* __restrict__ state,
    __half* __restrict__ fused, __half* __restrict__ reset)
{
    const int b = blockIdx.x;
    const int t = threadIdx.x;

    const float2 iv = *(const float2*)(inputs + (size_t)b * D_IN + t * 2);
    __half2 hv;
    hv.x = __float2half(iv.x);
    hv.y = __float2half(iv.y);
    *(__half2*)(fused + (size_t)b * FD + t * 2) = hv;
    *(__half2*)(reset + (size_t)b * FD + t * 2) = hv;

    const float4* sp = (const float4*)(state + (size_t)b * NRU + t * 16);
    float4 x0 = sp[0], x1 = sp[1], x2 = sp[2], x3 = sp[3];
    float s0 = (x0.x + x0.y) + (x0.z + x0.w) + (x1.x + x1.y) + (x1.z + x1.w);
    float s1 = (x2.x + x2.y) + (x2.z + x2.w) + (x3.x + x3.y) + (x3.z + x3.w);
    __half2 h2;
    h2.x = __float2half(s0);
    h2.y = __float2half(s1);
    *(__half2*)(fused + (size_t)b * FD + D_IN + t * 2) = h2;
}

// ---------------------------------------------------------------------------
// P2 (merged): transpose-convert W_r, W_u, W_d in one launch.
// ---------------------------------------------------------------------------
__global__ __launch_bounds__(256) void convT3_kernel(
    const float* __restrict__ W_r, const float* __restrict__ W_u,
    const float* __restrict__ W_d, __half* __restrict__ WruT,
    __half* __restrict__ WdT)
{
    __shared__ float tile[32][33];
    const int bx = blockIdx.x;
    const float* W;
    __half* Wt;
    int N, nt;
    if (bx < 128)      { W = W_r; Wt = WruT;                    N = NRU; nt = bx * 32; }
    else if (bx < 256) { W = W_u; Wt = WruT + (size_t)NRU * FD; N = NRU; nt = (bx - 128) * 32; }
    else               { W = W_d; Wt = WdT;                     N = U_N; nt = (bx - 256) * 32; }

    const int kt = blockIdx.y * 32;
    const int t  = threadIdx.x;
    const int c  = t & 31;
    const int r4 = t >> 5;

#pragma unroll
    for (int i = 0; i < 4; i++) {
        int r = r4 + i * 8;
        tile[r][c] = W[(size_t)(kt + r) * N + nt + c];
    }
    __syncthreads();
#pragma unroll
    for (int i = 0; i < 4; i++) {
        int rr = r4 + i * 8;
        Wt[(size_t)(nt + rr) * FD + kt + c] = __float2half(tile[c][rr]);
    }
}

// ---------------------------------------------------------------------------
// GEMM: [M,K](f16) @ [N,K](f16)^T, BMx128 tile, BK=64, m97-style.
// global_load_lds width-16 staging into XOR-swizzled LDS:
//   16B granule g of row r lives at slot r*8 + (g ^ (r&7)).
//   Staging stays a linear lane->slot burst (required by global_load_lds);
//   the lane's GLOBAL granule is permuted instead. Fragment ds_read_b128
//   then hits all 8 bank-groups across m16 (2-way alias = free, m136).
// EPI=0 (BM=64): qk[row][col] = tanhf(acc + biasA[col])   (detect path)
// EPI=1 (BM=128): fused CTGRU gate epilogue, coalesced mapping.
// ---------------------------------------------------------------------------
template <int BM, int EPI>
__global__ __launch_bounds__(256) void gemm_k(
    const __half* __restrict__ A, const __half* __restrict__ Bt,
    const float* __restrict__ biasA, const float* __restrict__ biasB, int nsplit,
    float* __restrict__ C, int Ncols,
    const float* __restrict__ state, __half* __restrict__ resetw,
    __half* __restrict__ skibuf, int K)
{
    extern __shared__ __align__(16) char smem[];
    __half* sA = (__half*)smem;                // [BM][64] swizzled
    __half* sB = (__half*)(smem + BM * 128);   // [128][64] swizzled

    const int t    = threadIdx.x;
    const int m0   = blockIdx.y * BM;
    const int n0   = blockIdx.x << 7;
    const int lane = t & 63;
    const int w    = t >> 6;
    const int m16  = lane & 15;
    const int quad = lane >> 4;
    constexpr int MI = BM / 32;       // m-frags per wave
    constexpr int IA = BM / 32;       // A staging instrs per wave
    const int wm = (w & 1) * (BM / 2);
    const int wn = (w >> 1) << 6;
    const int strip = w >> 1;

    f32x4 acc[MI][4];
#pragma unroll
    for (int i = 0; i < MI; i++)
#pragma unroll
        for (int j = 0; j < 4; j++)
#pragma unroll
            for (int r = 0; r < 4; r++) acc[i][j][r] = 0.f;

    const __half* gAp[IA];
    const __half* lAp[IA];
#pragma unroll
    for (int i = 0; i < IA; i++) {
        const int off = w * (BM * 32) + i * 1024 + lane * 16;  // byte off in tile
        const int row = off >> 7;
        const int g   = ((off & 127) >> 4) ^ (row & 7);        // swizzled global granule
        gAp[i] = A + (size_t)(m0 + row) * K + g * 8;
        lAp[i] = sA + ((w * (BM * 32) + i * 1024) >> 1);
    }
    const __half* gBp[4];
    const __half* lBp[4];
#pragma unroll
    for (int i = 0; i < 4; i++) {
        const int off = w * 4096 + i * 1024 + lane * 16;
        const int row = off >> 7;
        const int g   = ((off & 127) >> 4) ^ (row & 7);
        gBp[i] = Bt + (size_t)(n0 + row) * K + g * 8;
        lBp[i] = sB + ((w * 4096 + i * 1024) >> 1);
    }

    for (int kt = 0; kt < K; kt += 64) {
        __syncthreads();
#pragma unroll
        for (int i = 0; i < IA; i++)
            __builtin_amdgcn_global_load_lds((glb_cv*)(gAp[i] + kt), (lds_v*)lAp[i], 16, 0, 0);
#pragma unroll
        for (int i = 0; i < 4; i++)
            __builtin_amdgcn_global_load_lds((glb_cv*)(gBp[i] + kt), (lds_v*)lBp[i], 16, 0, 0);
        __syncthreads();

#pragma unroll
        for (int s = 0; s < 2; s++) {
            f16x8 af[MI], bf[4];
#pragma unroll
            for (int mi = 0; mi < MI; mi++) {
                const int row = wm + mi * 16 + m16;
                const int gi  = (s * 4 + quad) ^ (row & 7);
                af[mi] = *(const f16x8*)(sA + row * 64 + gi * 8);
            }
#pragma unroll
            for (int ni = 0; ni < 4; ni++) {
                const int row = wn + ni * 16 + m16;
                const int gi  = (s * 4 + quad) ^ (row & 7);
                bf[ni] = *(const f16x8*)(sB + row * 64 + gi * 8);
            }
#pragma unroll
            for (int mi = 0; mi < MI; mi++)
#pragma unroll
                for (int ni = 0; ni < 4; ni++)
                    acc[mi][ni] = __builtin_amdgcn_mfma_f32_16x16x32_f16(
                        af[mi], bf[ni], acc[mi][ni], 0, 0, 0);
        }
    }

    if constexpr (EPI == 0) {
        // -------- detect: tanh + plain store (BM == 64) --------
#pragma unroll
        for (int mi = 0; mi < MI; mi++) {
#pragma unroll
            for (int ni = 0; ni < 4; ni++) {
                const int col = n0 + wn + ni * 16 + m16;
                const float bv = biasA[col];
#pragma unroll
                for (int r = 0; r < 4; r++) {
                    const int row = m0 + wm + mi * 16 + quad * 4 + r;
                    C[(size_t)row * Ncols + col] = tanhf(acc[mi][ni][r] + bv);
                }
            }
        }
    } else {
        // -------- fused gate epilogue, coalesced (BM == 128) --------
        __syncthreads();
        float*  ebuf = (float*)smem;                    // [128][36]
        __half* qbuf = (__half*)(smem + 128 * 36 * 4);  // [128][16]
        const bool is_r = (n0 < nsplit);
        const float* bp = is_r ? biasA : biasB;
        const int n0r = is_r ? n0 : n0 - nsplit;   // col base in r/u space
        const float TAB[8] = TAB_INIT;
        const int ug  = t & 3;
        const int s   = ug >> 1;
        const int g   = ug & 1;
        const int bl0 = t >> 2;        // 0..63

        for (int ni = 0; ni < 4; ni++) {
            const float bv = bp[n0r + strip * 64 + ni * 16 + m16];
#pragma unroll
            for (int mi = 0; mi < 4; mi++)
#pragma unroll
                for (int r = 0; r < 4; r++)
                    ebuf[(wm + mi * 16 + quad * 4 + r) * 36 + strip * 16 + m16] =
                        acc[mi][ni][r] + bv;
            __syncthreads();

#pragma unroll
            for (int p = 0; p < 2; p++) {
                const int b_loc = bl0 + p * 64;
                const int b = m0 + b_loc;
                const float* rowp = ebuf + b_loc * 36 + ug * 8;
                float v[8];
                *(float4*)&v[0] = *(const float4*)rowp;
                *(float4*)&v[4] = *(const float4*)(rowp + 4);

                float e[8];
                float sum = 0.f;
#pragma unroll
                for (int i = 0; i < 8; i++) {
                    float d = v[i] - TAB[i];
                    e[i] = __expf(-d * d);
                    sum += e[i];
                }
                const int col = n0r + s * 64 + ni * 16 + g * 8;  // flat (u*8) col
                if (is_r) {
                    const float4 h0 = *(const float4*)(state + (size_t)b * NRU + col);
                    const float4 h1 = *(const float4*)(state + (size_t)b * NRU + col + 4);
                    const float hv[8] = {h0.x, h0.y, h0.z, h0.w, h1.x, h1.y, h1.z, h1.w};
                    float qn = 0.f;
#pragma unroll
                    for (int i = 0; i < 8; i++) qn += e[i] * hv[i];
                    qbuf[b_loc * 16 + (s * 8 + ni * 2 + g)] = __float2half(qn / sum);
                } else {
                    const float inv = 1.0f / sum;
                    __half2 o[4];
#pragma unroll
                    for (int i = 0; i < 4; i++) {
                        o[i].x = __float2half(e[2 * i] * inv);
                        o[i].y = __float2half(e[2 * i + 1] * inv);
                    }
                    *(uint4*)(skibuf + (size_t)b * NRU + col) = *(uint4*)o;
                }
            }
            __syncthreads();
        }
        if (is_r) {
            const int b_loc = t >> 1;
            const int j = t & 1;
            uint4 qv = *(uint4*)(qbuf + b_loc * 16 + j * 8);
            *(uint4*)(resetw + (size_t)(m0 + b_loc) * FD + D_IN + (n0r >> 3) + j * 8) = qv;
        }
    }
}

// ---------------------------------------------------------------------------
// E2: h_hat_next = ((1-ski)*h_hat + ski*qk) * exp(-el/tau); h_next = sum_m
// ---------------------------------------------------------------------------
__global__ __launch_bounds__(256) void final_kernel(
    const __half* __restrict__ skibuf, const float* __restrict__ state,
    const float* __restrict__ qk, const float* __restrict__ elapsed,
    float* __restrict__ out0, float* __restrict__ out1)
{
    const int idx = blockIdx.x * 256 + threadIdx.x;
    const int b = idx >> 9;
    const int u = idx & 511;

    const float INV_TAU[8] = {1.0f, 0.316227766016838f, 0.1f, 0.0316227766016838f,
                              0.01f, 0.00316227766016838f, 0.001f, 0.000316227766016838f};

    const uint4 sr = *(const uint4*)(skibuf + (size_t)b * NRU + u * 8);
    const __half2* sh = (const __half2*)&sr;
    float sk[8];
#pragma unroll
    for (int i = 0; i < 4; i++) {
        float2 f2 = __half22float2(sh[i]);
        sk[2 * i]     = f2.x;
        sk[2 * i + 1] = f2.y;
    }

    const float4* hh = (const float4*)(state + ((size_t)b * NRU + u * 8));
    float4 h0 = hh[0], h1 = hh[1];
    float h[8] = {h0.x, h0.y, h0.z, h0.w, h1.x, h1.y, h1.z, h1.w};

    const float q  = qk[(size_t)b * U_N + u];
    const float el = elapsed[b];

    float hn[8];
    float acc = 0.f;
#pragma unroll
    for (int i = 0; i < 8; i++) {
        const float et = __expf(-el * INV_TAU[i]);
        hn[i] = ((1.0f - sk[i]) * h[i] + sk[i] * q) * et;
        acc += hn[i];
    }

    float4* o = (float4*)(out1 + ((size_t)b * NRU + u * 8));
    o[0] = make_float4(hn[0], hn[1], hn[2], hn[3]);
    o[1] = make_float4(hn[4], hn[5], hn[6], hn[7]);
    out0[(size_t)b * U_N + u] = acc;
}

// ---------------------------------------------------------------------------
extern "C" void kernel_launch(void* const* d_in, const int* in_sizes, int n_in,
                              void* d_out, int out_size, void* d_ws, size_t ws_size,
                              hipStream_t stream)
{
    (void)in_sizes; (void)n_in; (void)out_size; (void)ws_size;

    const float* inputs  = (const float*)d_in[0];
    const float* elapsed = (const float*)d_in[1];
    const float* state   = (const float*)d_in[2];
    const float* W_r     = (const float*)d_in[3];
    const float* b_r     = (const float*)d_in[4];
    const float* W_d     = (const float*)d_in[5];
    const float* b_d     = (const float*)d_in[6];
    const float* W_u     = (const float*)d_in[7];
    const float* b_u     = (const float*)d_in[8];
    float* out = (float*)d_out;

    char* ws = (char*)d_ws;
    __half* fused  = (__half*)(ws);                         //  4 MB [2048,1024]
    __half* reset  = (__half*)(ws + ((size_t)4  << 20));    //  4 MB [2048,1024]
    __half* WruT   = (__half*)(ws + ((size_t)8  << 20));    // 16 MB [8192,1024]
    __half* WdT    = (__half*)(ws + ((size_t)24 << 20));    //  1 MB [512,1024]
    __half* skibuf = (__half*)(ws + ((size_t)25 << 20));    // 16 MB [2048,4096]
    float*  qk     = (float*) (ws + ((size_t)41 << 20));    //  4 MB [2048,512]

    prep_kernel<<<B_SZ, 256, 0, stream>>>(inputs, state, fused, reset);
    convT3_kernel<<<dim3(272, FD / 32), 256, 0, stream>>>(W_r, W_u, W_d, WruT, WdT);

    // combined r+u GEMM with fused gate epilogue: [2048,1024] x [8192,1024]^T
    gemm_k<128, 1><<<dim3(NRU2 / 128, B_SZ / 128), 256, 32768, stream>>>(
        fused, WruT, b_r, b_u, NRU, nullptr, 0, state, reset, skibuf, FD);

    // detect GEMM: [2048,1024] x [512,1024]^T -> qk fp32 (tanh)
    gemm_k<64, 0><<<dim3(U_N / 128, B_SZ / 64), 256, 24576, stream>>>(
        reset, WdT, b_d, nullptr, 1 << 30, qk, U_N, nullptr, nullptr, nullptr, FD);

    final_kernel<<<(B_SZ * U_N) / 256, 256, 0, stream>>>(skibuf, state, qk, elapsed, out,
                                                         out + (size_t)B_SZ * U_N);
}